// Round 10
// baseline (80.611 us; speedup 1.0000x reference)
//
#include <hip/hip_runtime.h>
#include <math.h>

#define D    128
#define BSH  7          // 128 nodes per bucket
#define BSZ  128
#define GB1  512        // blocks for hist/scatter passes (== scan row length)
#define KT   512        // threads per block for sort kernels
#define STAGE_CAP 8192  // LDS staging capacity (edges) in k_csr

// ---- K1: bucket histogram of dst>>7 + per-block W12 (LDS) + z = x@W12 ----
__global__ __launch_bounds__(KT) void k_hist_z(
        const int* __restrict__ dst, int* __restrict__ hist_t,
        const float* __restrict__ W1, const float* __restrict__ b1,
        const float* __restrict__ W2, float* __restrict__ cvec,
        const float* __restrict__ x, float4* __restrict__ zd,
        int N, int E, int NB) {
    __shared__ int   h[512];
    __shared__ float wtmp[512];
    __shared__ float w12s[256];
    int t = threadIdx.x, b = blockIdx.x, B = gridDim.x;

    // W12 partials (each of 256 outputs split across 2 threads)
    {
        int idx = t >> 1, half = t & 1;       // idx in [0,256)
        int k = idx >> 1, c = idx & 1;
        float acc = 0.f;
        int m0 = half * 64;
        for (int m = m0; m < m0 + 64; ++m) acc += W1[k * D + m] * W2[m * 2 + c];
        wtmp[t] = acc;
    }
    for (int i = t; i < NB; i += KT) h[i] = 0;
    __syncthreads();
    if (t < 256) w12s[t] = wtmp[2 * t] + wtmp[2 * t + 1];
    if (b == 0 && t < 2) {
        float s = 0.f;
        for (int m = 0; m < D; ++m) s += b1[m] * W2[m * 2 + t];
        cvec[t] = s;
    }
    // histogram of dst high bits
    if ((E & 3) == 0) {
        const int4* dst4 = (const int4*)dst;
        int nq = E >> 2;
        int cq = (nq + B - 1) / B;
        int lo = b * cq, hi = min(nq, lo + cq);
        for (int i = lo + t; i < hi; i += KT) {
            int4 dv = dst4[i];
            atomicAdd(&h[dv.x >> BSH], 1);
            atomicAdd(&h[dv.y >> BSH], 1);
            atomicAdd(&h[dv.z >> BSH], 1);
            atomicAdd(&h[dv.w >> BSH], 1);
        }
    } else {
        int ce = (E + B - 1) / B;
        int lo = b * ce, hi = min(E, lo + ce);
        for (int i = lo + t; i < hi; i += KT) atomicAdd(&h[dst[i] >> BSH], 1);
    }
    __syncthreads();   // hist complete AND w12s complete
    for (int i = t; i < NB; i += KT) hist_t[i * B + b] = h[i];

    // ---- z = x @ W12 (LDS copy), one wave per node row -> zd.xy ----
    int lane = t & 63, w = t >> 6;
    int nwaves = B * (KT >> 6);
    int wid = b * (KT >> 6) + w;
    float4 wv = *(const float4*)(&w12s[lane * 4]);
    for (int node = wid; node < N; node += nwaves) {
        float2 xv = *(const float2*)(x + (size_t)node * D + lane * 2);
        float p0 = fmaf(xv.x, wv.x, xv.y * wv.z);
        float p1 = fmaf(xv.x, wv.y, xv.y * wv.w);
#pragma unroll
        for (int o = 32; o > 0; o >>= 1) {
            p0 += __shfl_xor(p0, o);
            p1 += __shfl_xor(p1, o);
        }
        if (lane == 0) {
            float2 r; r.x = p0; r.y = p1;
            *(float2*)&zd[node] = r;          // .z (dinv) written later in k_csr
        }
    }
}

// ---- K2: per-digit exclusive scan over GB1 block-counts; dsum; rowstart[N]=E ----
__global__ void k_scan_digit(int* __restrict__ hist_t, int* __restrict__ dsum,
                             int* __restrict__ rowstart, int N, int E) {
    __shared__ int wtot[8];
    int d = blockIdx.x, t = threadIdx.x, lane = t & 63, w = t >> 6;
    int v = hist_t[d * GB1 + t];
    int inc = v;
#pragma unroll
    for (int o = 1; o < 64; o <<= 1) {
        int n = __shfl_up(inc, o);
        if (lane >= o) inc += n;
    }
    if (lane == 63) wtot[w] = inc;
    __syncthreads();
    if (t < 8) {
        int x = wtot[t];
#pragma unroll
        for (int o = 1; o < 8; o <<= 1) {
            int n = __shfl_up(x, o, 8);
            if (t >= o) x += n;
        }
        wtot[t] = x;   // inclusive wave totals
    }
    __syncthreads();
    int woff = (w == 0) ? 0 : wtot[w - 1];
    hist_t[d * GB1 + t] = woff + inc - v;     // exclusive
    if (t == KT - 1) dsum[d] = wtot[7];
    if (d == 0 && t == 0) rowstart[N] = E;    // sentinel
}

// helper: in-block exclusive scan of dsum[0..NB) across 512 threads -> excl for t
__device__ __forceinline__ int block_scan_dsum(const int* __restrict__ dsum, int NB,
                                               int* wtot /*shared[8]*/) {
    int t = threadIdx.x, lane = t & 63, w = t >> 6;
    int v = (t < NB) ? dsum[t] : 0;
    int inc = v;
#pragma unroll
    for (int o = 1; o < 64; o <<= 1) {
        int n = __shfl_up(inc, o);
        if (lane >= o) inc += n;
    }
    if (lane == 63) wtot[w] = inc;
    __syncthreads();
    if (t < 8) {
        int x = wtot[t];
#pragma unroll
        for (int o = 1; o < 8; o <<= 1) {
            int n = __shfl_up(x, o, 8);
            if (t >= o) x += n;
        }
        wtot[t] = x;
    }
    __syncthreads();
    int woff = (w == 0) ? 0 : wtot[w - 1];
    return woff + inc - v;
}

// ---- K3: route edges into buckets (in-block bucket-start scan from dsum) ----
__global__ __launch_bounds__(KT) void k_scatter_pairs(
        const int* __restrict__ src, const int* __restrict__ dst,
        const int* __restrict__ hist_t, const int* __restrict__ dsum,
        unsigned* __restrict__ pairs, int E, int NB) {
    __shared__ int cur[512];
    __shared__ int wtot[8];
    int t = threadIdx.x, b = blockIdx.x, B = gridDim.x;
    int bsti = block_scan_dsum(dsum, NB, wtot);
    if (t < NB) cur[t] = hist_t[t * B + b] + bsti;
    __syncthreads();
    if ((E & 3) == 0) {
        const int4* dst4 = (const int4*)dst;
        const int4* src4 = (const int4*)src;
        int nq = E >> 2;
        int cq = (nq + B - 1) / B;
        int lo = b * cq, hi = min(nq, lo + cq);
        for (int i = lo + t; i < hi; i += KT) {
            int4 dv = dst4[i];
            int4 sv = src4[i];
            int p0 = atomicAdd(&cur[dv.x >> BSH], 1);
            pairs[p0] = ((unsigned)(dv.x & (BSZ - 1)) << 20) | (unsigned)sv.x;
            int p1 = atomicAdd(&cur[dv.y >> BSH], 1);
            pairs[p1] = ((unsigned)(dv.y & (BSZ - 1)) << 20) | (unsigned)sv.y;
            int p2 = atomicAdd(&cur[dv.z >> BSH], 1);
            pairs[p2] = ((unsigned)(dv.z & (BSZ - 1)) << 20) | (unsigned)sv.z;
            int p3 = atomicAdd(&cur[dv.w >> BSH], 1);
            pairs[p3] = ((unsigned)(dv.w & (BSZ - 1)) << 20) | (unsigned)sv.w;
        }
    } else {
        int ce = (E + B - 1) / B;
        int lo = b * ce, hi = min(E, lo + ce);
        for (int i = lo + t; i < hi; i += KT) {
            int d = dst[i];
            int p = atomicAdd(&cur[d >> BSH], 1);
            pairs[p] = ((unsigned)(d & (BSZ - 1)) << 20) | (unsigned)src[i];
        }
    }
}

// ---- K4: per-bucket node-sort (LDS-staged) -> csr + rowstart + dinv(zd.z) ----
__global__ __launch_bounds__(KT) void k_csr(
        const unsigned* __restrict__ pairs, const int* __restrict__ dsum,
        int* __restrict__ csr, int* __restrict__ rowstart,
        float4* __restrict__ zd, int N, int E, int NB) {
    __shared__ unsigned stage[STAGE_CAP];
    __shared__ int bstall[512];
    __shared__ int h[BSZ];
    __shared__ int wtot[8];
    int t = threadIdx.x, bb = blockIdx.x;
    int lane = t & 63, w = t >> 6;

    int bsti = block_scan_dsum(dsum, NB, wtot);
    bstall[t] = bsti;
    __syncthreads();
    int bs = bstall[bb];
    int be = bstall[bb + 1];                 // t=NB scan value == E (NB < 512)
    int ne = be - bs;

    if (t < BSZ) h[t] = 0;
    __syncthreads();
    bool fits = (ne <= STAGE_CAP);
    if (fits) {
        for (int i = t; i < ne; i += KT) {
            unsigned p = pairs[bs + i];
            stage[i] = p;
            atomicAdd(&h[p >> 20], 1);
        }
    } else {
        for (int i = t; i < ne; i += KT) atomicAdd(&h[pairs[bs + i] >> 20], 1);
    }
    __syncthreads();
    int v = 0, inc = 0;
    if (t < BSZ) {
        v = h[t];
        inc = v;
#pragma unroll
        for (int o = 1; o < 64; o <<= 1) {
            int n = __shfl_up(inc, o);
            if (lane >= o) inc += n;
        }
        if (lane == 63) wtot[w] = inc;       // waves 0,1 only
    }
    __syncthreads();
    if (t < BSZ) {
        int excl = ((w == 1) ? wtot[0] : 0) + inc - v;
        int node = (bb << BSH) + t;
        if (node < N) {
            rowstart[node] = bs + excl;
            zd[node].z = rsqrtf((float)(v + 1));
        }
        h[t] = excl;                         // bucket-relative scatter cursor
    }
    __syncthreads();
    if (fits) {
        for (int i = t; i < ne; i += KT) {
            unsigned p = stage[i];
            int pos = bs + atomicAdd(&h[p >> 20], 1);
            csr[pos] = (int)(p & 0xFFFFFu);
        }
    } else {
        for (int i = t; i < ne; i += KT) {
            unsigned p = pairs[bs + i];
            int pos = bs + atomicAdd(&h[p >> 20], 1);
            csr[pos] = (int)(p & 0xFFFFFu);
        }
    }
}

// ---- K5: gather A (16 lanes/node, register acc) -> aw = (w*a1x, w*a1y, srow, w) ----
__global__ void k_gatherA(const int* __restrict__ csr, const int* __restrict__ rowstart,
                          const float4* __restrict__ zd, float4* __restrict__ aw, int N) {
    int g = blockIdx.x * blockDim.x + threadIdx.x;
    int node = g >> 4, lane = threadIdx.x & 15;
    if (node >= N) return;
    int rs = rowstart[node], re = rowstart[node + 1];
    float acc0 = 0.f, acc1 = 0.f, sw = 0.f;
    for (int j = rs + lane; j < re; j += 16) {
        int s = csr[j];
        float4 zv = zd[s];                     // (z0, z1, dinv, -)
        acc0 = fmaf(zv.z, zv.x, acc0);
        acc1 = fmaf(zv.z, zv.y, acc1);
        sw  += zv.z;
    }
#pragma unroll
    for (int o = 8; o > 0; o >>= 1) {
        acc0 += __shfl_xor(acc0, o);
        acc1 += __shfl_xor(acc1, o);
        sw   += __shfl_xor(sw, o);
    }
    if (lane == 0) {
        float4 zv = zd[node];
        float wd = zv.z;
        float a1x  = wd * (acc0 + wd * zv.x);
        float a1y  = wd * (acc1 + wd * zv.y);
        float srow = wd * (sw + wd);
        aw[node] = make_float4(wd * a1x, wd * a1y, srow, wd);
    }
}

// ---- K6: gather B (16 lanes/node) + rank-1 bias + gumbel softmax epilogue ----
__global__ void k_gatherB(const int* __restrict__ csr, const int* __restrict__ rowstart,
                          const float4* __restrict__ aw, const float* __restrict__ cvec,
                          const float* __restrict__ b2, const float2* __restrict__ noise,
                          float2* __restrict__ out, int N) {
    int g = blockIdx.x * blockDim.x + threadIdx.x;
    int node = g >> 4, lane = threadIdx.x & 15;
    if (node >= N) return;
    int rs = rowstart[node], re = rowstart[node + 1];
    float acc0 = 0.f, acc1 = 0.f;
    for (int j = rs + lane; j < re; j += 16) {
        int s = csr[j];
        float4 av = aw[s];                     // (w*a1x, w*a1y, srow, w)
        acc0 += av.x;
        acc1 += av.y;
    }
#pragma unroll
    for (int o = 8; o > 0; o >>= 1) {
        acc0 += __shfl_xor(acc0, o);
        acc1 += __shfl_xor(acc1, o);
    }
    if (lane == 0) {
        float4 av = aw[node];
        float wd = av.w;
        float l0 = wd * (acc0 + av.x) + av.z * cvec[0] + b2[0];
        float l1 = wd * (acc1 + av.y) + av.z * cvec[1] + b2[1];
        const float EPS = 1e-9f;
        float2 nv = noise[node];
        float g0 = -logf(-logf(nv.x + EPS) + EPS);
        float g1 = -logf(-logf(nv.y + EPS) + EPS);
        float u0 = (l0 + g0) * 2.0f;
        float u1 = (l1 + g1) * 2.0f;
        float m = fmaxf(u0, u1);
        float e0 = __expf(u0 - m), e1 = __expf(u1 - m);
        float inv = 1.0f / (e0 + e1);
        float2 r; r.x = e0 * inv; r.y = e1 * inv;
        out[node] = r;
    }
}

extern "C" void kernel_launch(void* const* d_in, const int* in_sizes, int n_in,
                              void* d_out, int out_size, void* d_ws, size_t ws_size,
                              hipStream_t stream) {
    const float* x     = (const float*)d_in[0];
    const int*   ei    = (const int*)d_in[1];
    const float* W1    = (const float*)d_in[2];
    const float* b1    = (const float*)d_in[3];
    const float* W2    = (const float*)d_in[4];
    const float* b2    = (const float*)d_in[5];
    const float* noise = (const float*)d_in[6];
    float* out = (float*)d_out;

    const int N = in_sizes[0] / D;
    const int E = in_sizes[1] / 2;
    const int* src = ei;
    const int* dst = ei + E;
    const int NB = (N + BSZ - 1) >> BSH;       // buckets of 128 nodes (<512)

    // ---- workspace carve (16B-aligned chunks first) ----
    char* p = (char*)d_ws;
    float4*   zd       = (float4*)p;   p += (size_t)N * 16;
    float4*   aw       = (float4*)p;   p += (size_t)N * 16;
    unsigned* pairs    = (unsigned*)p; p += (size_t)E * 4;
    int*      csr      = (int*)p;      p += (size_t)E * 4;
    int*      rowstart = (int*)p;      p += (size_t)(N + 4) * 4;
    int*      hist_t   = (int*)p;      p += (size_t)512 * GB1 * 4;   // 1 MB
    int*      dsum     = (int*)p;      p += 512 * 4;
    float*    cvec     = (float*)p;    p += 16;

    int g16 = (N * 16 + 255) / 256;            // 16 lanes/node, 256-thr blocks

    k_hist_z<<<GB1, KT, 0, stream>>>(dst, hist_t, W1, b1, W2, cvec, x, zd, N, E, NB);
    k_scan_digit<<<NB, KT, 0, stream>>>(hist_t, dsum, rowstart, N, E);
    k_scatter_pairs<<<GB1, KT, 0, stream>>>(src, dst, hist_t, dsum, pairs, E, NB);
    k_csr<<<NB, KT, 0, stream>>>(pairs, dsum, csr, rowstart, zd, N, E, NB);
    k_gatherA<<<g16, 256, 0, stream>>>(csr, rowstart, zd, aw, N);
    k_gatherB<<<g16, 256, 0, stream>>>(csr, rowstart, aw, cvec, b2, (const float2*)noise,
                                       (float2*)out, N);
}

// Round 11
// 79.529 us; speedup vs baseline: 1.0136x; 1.0136x over previous
//
#include <hip/hip_runtime.h>
#include <math.h>

#define D    128
#define BSH  7          // 128 nodes per bucket
#define BSZ  128
#define CAP  8192       // fixed slot capacity per bucket (~64 sigma of mean 4096)
#define GB1  512        // blocks for the scatter kernel
#define KT   512        // threads per block for sort kernels
#define SCAP 3200       // LDS edge-staging capacity in k_scatter_res

// ---- K1: chunk-staged scatter with atomic slot reservation; W12/cvec on block 0 ----
__global__ __launch_bounds__(KT) void k_scatter_res(
        const int* __restrict__ src, const int* __restrict__ dst,
        int* __restrict__ counts, unsigned* __restrict__ pairs,
        const float* __restrict__ W1, const float* __restrict__ b1,
        const float* __restrict__ W2,
        float* __restrict__ W12, float* __restrict__ cvec, int E, int NB) {
    __shared__ unsigned       plds[SCAP];
    __shared__ unsigned short blds[SCAP];
    __shared__ int            h[512];
    __shared__ float          wtmp[512];
    int t = threadIdx.x, b = blockIdx.x, B = gridDim.x;

    if ((E & 3) == 0) {
        const int4* dst4 = (const int4*)dst;
        const int4* src4 = (const int4*)src;
        int nq = E >> 2, cq = (nq + B - 1) / B;
        int lo = b * cq, hi = min(nq, lo + cq);
        for (int tl = lo; tl < hi; tl += SCAP / 4) {
            int th = min(hi, tl + SCAP / 4);
            int ne = (th - tl) * 4;
            for (int i = t; i < NB; i += KT) h[i] = 0;
            __syncthreads();
            for (int j = tl + t; j < th; j += KT) {
                int4 dv = dst4[j];
                int4 sv = src4[j];
                int li = (j - tl) * 4;
                int b0 = dv.x >> BSH;
                plds[li + 0] = ((unsigned)(dv.x & (BSZ - 1)) << 20) | (unsigned)sv.x;
                blds[li + 0] = (unsigned short)b0; atomicAdd(&h[b0], 1);
                int b1i = dv.y >> BSH;
                plds[li + 1] = ((unsigned)(dv.y & (BSZ - 1)) << 20) | (unsigned)sv.y;
                blds[li + 1] = (unsigned short)b1i; atomicAdd(&h[b1i], 1);
                int b2i = dv.z >> BSH;
                plds[li + 2] = ((unsigned)(dv.z & (BSZ - 1)) << 20) | (unsigned)sv.z;
                blds[li + 2] = (unsigned short)b2i; atomicAdd(&h[b2i], 1);
                int b3i = dv.w >> BSH;
                plds[li + 3] = ((unsigned)(dv.w & (BSZ - 1)) << 20) | (unsigned)sv.w;
                blds[li + 3] = (unsigned short)b3i; atomicAdd(&h[b3i], 1);
            }
            __syncthreads();
            int myh = (t < NB) ? h[t] : 0;
            int mb = 0;
            if (t < NB && myh) mb = atomicAdd(&counts[t], myh);  // reserve slots
            if (t < NB) h[t] = t * CAP + mb;                     // global cursor
            __syncthreads();
            for (int li = t; li < ne; li += KT) {
                int pos = atomicAdd(&h[blds[li]], 1);
                pairs[pos] = plds[li];
            }
            __syncthreads();
        }
    } else {
        int ce = (E + B - 1) / B;
        int lo = b * ce, hi = min(E, lo + ce);
        for (int tl = lo; tl < hi; tl += SCAP) {
            int th = min(hi, tl + SCAP);
            int ne = th - tl;
            for (int i = t; i < NB; i += KT) h[i] = 0;
            __syncthreads();
            for (int i = tl + t; i < th; i += KT) {
                int d = dst[i];
                int bkt = d >> BSH;
                int li = i - tl;
                plds[li] = ((unsigned)(d & (BSZ - 1)) << 20) | (unsigned)src[i];
                blds[li] = (unsigned short)bkt;
                atomicAdd(&h[bkt], 1);
            }
            __syncthreads();
            int myh = (t < NB) ? h[t] : 0;
            int mb = 0;
            if (t < NB && myh) mb = atomicAdd(&counts[t], myh);
            if (t < NB) h[t] = t * CAP + mb;
            __syncthreads();
            for (int li = t; li < ne; li += KT) {
                int pos = atomicAdd(&h[blds[li]], 1);
                pairs[pos] = plds[li];
            }
            __syncthreads();
        }
    }

    // ---- W12 = W1@W2 and cvec = b1^T W2, block 0 only ----
    if (b == 0) {
        int idx = t >> 1, half = t & 1;       // idx in [0,256)
        int k = idx >> 1, c = idx & 1;
        float acc = 0.f;
        int m0 = half * 64;
        for (int m = m0; m < m0 + 64; ++m) acc += W1[k * D + m] * W2[m * 2 + c];
        wtmp[t] = acc;
        __syncthreads();
        if (half == 0) W12[idx] = wtmp[t] + wtmp[t + 1];
        if (t < 2) {
            float s = 0.f;
            for (int m = 0; m < D; ++m) s += b1[m] * W2[m * 2 + t];
            cvec[t] = s;
        }
    }
}

// ---- K2: per-bucket node-sort (LDS-staged) -> csr + rowstart/rowend + dinv; z tail ----
__global__ __launch_bounds__(KT) void k_csr_z(
        const unsigned* __restrict__ pairs, const int* __restrict__ counts,
        const float* __restrict__ x, const float* __restrict__ W12,
        int* __restrict__ csr, int* __restrict__ rowstart, int* __restrict__ rowend,
        float4* __restrict__ zd, int N, int NB) {
    __shared__ unsigned stage[CAP];
    __shared__ int h[BSZ];
    __shared__ int wtot[2];
    int t = threadIdx.x, b = blockIdx.x, B = gridDim.x;
    int lane = t & 63, w = t >> 6;

    for (int bb = b; bb < NB; bb += B) {
        int bs = bb * CAP;
        int ne = min(counts[bb], CAP);
        if (t < BSZ) h[t] = 0;
        __syncthreads();
        for (int i = t; i < ne; i += KT) {
            unsigned p = pairs[bs + i];
            stage[i] = p;
            atomicAdd(&h[p >> 20], 1);
        }
        __syncthreads();
        int v = 0, inc = 0;
        if (t < BSZ) {
            v = h[t];
            inc = v;
#pragma unroll
            for (int o = 1; o < 64; o <<= 1) {
                int n = __shfl_up(inc, o);
                if (lane >= o) inc += n;
            }
            if (lane == 63) wtot[w] = inc;   // waves 0,1 only
        }
        __syncthreads();
        if (t < BSZ) {
            int excl = ((w == 1) ? wtot[0] : 0) + inc - v;
            int node = (bb << BSH) + t;
            if (node < N) {
                rowstart[node] = bs + excl;
                rowend[node]   = bs + excl + v;
                zd[node].z = rsqrtf((float)(v + 1));
            }
            h[t] = excl;                     // bucket-relative scatter cursor
        }
        __syncthreads();
        for (int i = t; i < ne; i += KT) {
            unsigned p = stage[i];
            int pos = bs + atomicAdd(&h[p >> 20], 1);
            csr[pos] = (int)(p & 0xFFFFFu);
        }
        __syncthreads();
    }

    // ---- z = x @ W12, one wave per node row (writes zd.xy; .z disjoint) ----
    int nwaves = B * (KT >> 6);
    int wid = b * (KT >> 6) + w;
    float4 wv = *(const float4*)(W12 + lane * 4);
    for (int node = wid; node < N; node += nwaves) {
        float2 xv = *(const float2*)(x + (size_t)node * D + lane * 2);
        float p0 = fmaf(xv.x, wv.x, xv.y * wv.z);
        float p1 = fmaf(xv.x, wv.y, xv.y * wv.w);
#pragma unroll
        for (int o = 32; o > 0; o >>= 1) {
            p0 += __shfl_xor(p0, o);
            p1 += __shfl_xor(p1, o);
        }
        if (lane == 0) {
            float2 r; r.x = p0; r.y = p1;
            *(float2*)&zd[node] = r;
        }
    }
}

// ---- K3: gather A (16 lanes/node, register acc) -> aw = (w*a1x, w*a1y, srow, w) ----
__global__ void k_gatherA(const int* __restrict__ csr, const int* __restrict__ rowstart,
                          const int* __restrict__ rowend,
                          const float4* __restrict__ zd, float4* __restrict__ aw, int N) {
    int g = blockIdx.x * blockDim.x + threadIdx.x;
    int node = g >> 4, lane = threadIdx.x & 15;
    if (node >= N) return;
    int rs = rowstart[node], re = rowend[node];
    float acc0 = 0.f, acc1 = 0.f, sw = 0.f;
    for (int j = rs + lane; j < re; j += 16) {
        int s = csr[j];
        float4 zv = zd[s];                     // (z0, z1, dinv, -)
        acc0 = fmaf(zv.z, zv.x, acc0);
        acc1 = fmaf(zv.z, zv.y, acc1);
        sw  += zv.z;
    }
#pragma unroll
    for (int o = 8; o > 0; o >>= 1) {
        acc0 += __shfl_xor(acc0, o);
        acc1 += __shfl_xor(acc1, o);
        sw   += __shfl_xor(sw, o);
    }
    if (lane == 0) {
        float4 zv = zd[node];
        float wd = zv.z;
        float a1x  = wd * (acc0 + wd * zv.x);
        float a1y  = wd * (acc1 + wd * zv.y);
        float srow = wd * (sw + wd);
        aw[node] = make_float4(wd * a1x, wd * a1y, srow, wd);
    }
}

// ---- K4: gather B (16 lanes/node) + rank-1 bias + gumbel softmax epilogue ----
__global__ void k_gatherB(const int* __restrict__ csr, const int* __restrict__ rowstart,
                          const int* __restrict__ rowend,
                          const float4* __restrict__ aw, const float* __restrict__ cvec,
                          const float* __restrict__ b2, const float2* __restrict__ noise,
                          float2* __restrict__ out, int N) {
    int g = blockIdx.x * blockDim.x + threadIdx.x;
    int node = g >> 4, lane = threadIdx.x & 15;
    if (node >= N) return;
    int rs = rowstart[node], re = rowend[node];
    float acc0 = 0.f, acc1 = 0.f;
    for (int j = rs + lane; j < re; j += 16) {
        int s = csr[j];
        float4 av = aw[s];                     // (w*a1x, w*a1y, srow, w)
        acc0 += av.x;
        acc1 += av.y;
    }
#pragma unroll
    for (int o = 8; o > 0; o >>= 1) {
        acc0 += __shfl_xor(acc0, o);
        acc1 += __shfl_xor(acc1, o);
    }
    if (lane == 0) {
        float4 av = aw[node];
        float wd = av.w;
        float l0 = wd * (acc0 + av.x) + av.z * cvec[0] + b2[0];
        float l1 = wd * (acc1 + av.y) + av.z * cvec[1] + b2[1];
        const float EPS = 1e-9f;
        float2 nv = noise[node];
        float g0 = -logf(-logf(nv.x + EPS) + EPS);
        float g1 = -logf(-logf(nv.y + EPS) + EPS);
        float u0 = (l0 + g0) * 2.0f;
        float u1 = (l1 + g1) * 2.0f;
        float m = fmaxf(u0, u1);
        float e0 = __expf(u0 - m), e1 = __expf(u1 - m);
        float inv = 1.0f / (e0 + e1);
        float2 r; r.x = e0 * inv; r.y = e1 * inv;
        out[node] = r;
    }
}

extern "C" void kernel_launch(void* const* d_in, const int* in_sizes, int n_in,
                              void* d_out, int out_size, void* d_ws, size_t ws_size,
                              hipStream_t stream) {
    const float* x     = (const float*)d_in[0];
    const int*   ei    = (const int*)d_in[1];
    const float* W1    = (const float*)d_in[2];
    const float* b1    = (const float*)d_in[3];
    const float* W2    = (const float*)d_in[4];
    const float* b2    = (const float*)d_in[5];
    const float* noise = (const float*)d_in[6];
    float* out = (float*)d_out;

    const int N = in_sizes[0] / D;
    const int E = in_sizes[1] / 2;
    const int* src = ei;
    const int* dst = ei + E;
    const int NB = (N + BSZ - 1) >> BSH;       // buckets of 128 nodes (<512)

    // ---- workspace carve (16B-aligned chunks first) ----
    char* p = (char*)d_ws;
    float4*   zd       = (float4*)p;   p += (size_t)N * 16;
    float4*   aw       = (float4*)p;   p += (size_t)N * 16;
    unsigned* pairs    = (unsigned*)p; p += (size_t)NB * CAP * 4;   // padded buckets
    int*      csr      = (int*)p;      p += (size_t)NB * CAP * 4;   // padded layout
    int*      rowstart = (int*)p;      p += (size_t)(N + 4) * 4;
    int*      rowend   = (int*)p;      p += (size_t)(N + 4) * 4;
    int*      counts   = (int*)p;      p += 512 * 4;
    float*    W12      = (float*)p;    p += 256 * 4;
    float*    cvec     = (float*)p;    p += 16;

    int g16 = (N * 16 + 255) / 256;            // 16 lanes/node, 256-thr blocks

    hipMemsetAsync(counts, 0, 512 * sizeof(int), stream);
    k_scatter_res<<<GB1, KT, 0, stream>>>(src, dst, counts, pairs, W1, b1, W2,
                                          W12, cvec, E, NB);
    k_csr_z<<<1024, KT, 0, stream>>>(pairs, counts, x, W12, csr, rowstart, rowend,
                                     zd, N, NB);
    k_gatherA<<<g16, 256, 0, stream>>>(csr, rowstart, rowend, zd, aw, N);
    k_gatherB<<<g16, 256, 0, stream>>>(csr, rowstart, rowend, aw, cvec, b2,
                                       (const float2*)noise, (float2*)out, N);
}

// Round 12
// 71.950 us; speedup vs baseline: 1.1204x; 1.1053x over previous
//
#include <hip/hip_runtime.h>
#include <math.h>

#define D    128
#define BSH  7          // 128 nodes per bucket
#define BSZ  128
#define GB1  512        // blocks for hist/scatter passes (== scan row length)
#define KT   512        // threads per block for sort kernels
#define STAGE_CAP 8192  // LDS staging capacity (edges) in k_csr_z

// ---- K1: bucket histogram of dst>>7 (digit-major table) + W12/cvec on block 0 ----
__global__ void k_hist(const int* __restrict__ dst, int* __restrict__ hist_t,
                       const float* __restrict__ W1, const float* __restrict__ b1,
                       const float* __restrict__ W2,
                       float* __restrict__ W12, float* __restrict__ cvec,
                       int E, int NB) {
    __shared__ int   h[512];
    __shared__ float wtmp[512];
    int t = threadIdx.x, b = blockIdx.x, B = gridDim.x;
    for (int i = t; i < NB; i += KT) h[i] = 0;
    __syncthreads();
    if ((E & 3) == 0) {
        const int4* dst4 = (const int4*)dst;
        int nq = E >> 2;
        int cq = (nq + B - 1) / B;
        int lo = b * cq, hi = min(nq, lo + cq);
        for (int i = lo + t; i < hi; i += KT) {
            int4 dv = dst4[i];
            atomicAdd(&h[dv.x >> BSH], 1);
            atomicAdd(&h[dv.y >> BSH], 1);
            atomicAdd(&h[dv.z >> BSH], 1);
            atomicAdd(&h[dv.w >> BSH], 1);
        }
    } else {
        int ce = (E + B - 1) / B;
        int lo = b * ce, hi = min(E, lo + ce);
        for (int i = lo + t; i < hi; i += KT) atomicAdd(&h[dst[i] >> BSH], 1);
    }
    __syncthreads();
    for (int i = t; i < NB; i += KT) hist_t[i * B + b] = h[i];
    if (b == 0) {
        int idx = t >> 1, half = t & 1;       // idx in [0,256)
        int k = idx >> 1, c = idx & 1;
        float acc = 0.f;
        int m0 = half * 64;
        for (int m = m0; m < m0 + 64; ++m) acc += W1[k * D + m] * W2[m * 2 + c];
        wtmp[t] = acc;
        __syncthreads();
        if (half == 0) W12[idx] = wtmp[t] + wtmp[t + 1];
        if (t < 2) {
            float s = 0.f;
            for (int m = 0; m < D; ++m) s += b1[m] * W2[m * 2 + t];
            cvec[t] = s;
        }
    }
}

// ---- K2: per-digit exclusive scan over GB1 block-counts; dsum; rowstart[N]=E ----
__global__ void k_scan_digit(int* __restrict__ hist_t, int* __restrict__ dsum,
                             int* __restrict__ rowstart, int N, int E) {
    __shared__ int wtot[8];
    int d = blockIdx.x, t = threadIdx.x, lane = t & 63, w = t >> 6;
    int v = hist_t[d * GB1 + t];
    int inc = v;
#pragma unroll
    for (int o = 1; o < 64; o <<= 1) {
        int n = __shfl_up(inc, o);
        if (lane >= o) inc += n;
    }
    if (lane == 63) wtot[w] = inc;
    __syncthreads();
    if (t < 8) {
        int x = wtot[t];
#pragma unroll
        for (int o = 1; o < 8; o <<= 1) {
            int n = __shfl_up(x, o, 8);
            if (t >= o) x += n;
        }
        wtot[t] = x;   // inclusive wave totals
    }
    __syncthreads();
    int woff = (w == 0) ? 0 : wtot[w - 1];
    hist_t[d * GB1 + t] = woff + inc - v;     // exclusive
    if (t == KT - 1) dsum[d] = wtot[7];
    if (d == 0 && t == 0) rowstart[N] = E;    // sentinel (no dependency)
}

// helper: in-block exclusive scan of dsum[0..NB) across 512 threads -> excl for t
__device__ __forceinline__ int block_scan_dsum(const int* __restrict__ dsum, int NB,
                                               int* wtot /*shared[8]*/) {
    int t = threadIdx.x, lane = t & 63, w = t >> 6;
    int v = (t < NB) ? dsum[t] : 0;
    int inc = v;
#pragma unroll
    for (int o = 1; o < 64; o <<= 1) {
        int n = __shfl_up(inc, o);
        if (lane >= o) inc += n;
    }
    if (lane == 63) wtot[w] = inc;
    __syncthreads();
    if (t < 8) {
        int x = wtot[t];
#pragma unroll
        for (int o = 1; o < 8; o <<= 1) {
            int n = __shfl_up(x, o, 8);
            if (t >= o) x += n;
        }
        wtot[t] = x;
    }
    __syncthreads();
    int woff = (w == 0) ? 0 : wtot[w - 1];
    return woff + inc - v;
}

// ---- K3: route edges into buckets (in-block bucket-start scan from dsum) ----
__global__ void k_scatter_pairs(const int* __restrict__ src, const int* __restrict__ dst,
                                const int* __restrict__ hist_t, const int* __restrict__ dsum,
                                unsigned* __restrict__ pairs, int E, int NB) {
    __shared__ int cur[512];
    __shared__ int wtot[8];
    int t = threadIdx.x, b = blockIdx.x, B = gridDim.x;
    int bsti = block_scan_dsum(dsum, NB, wtot);
    if (t < NB) cur[t] = hist_t[t * B + b] + bsti;
    __syncthreads();
    if ((E & 3) == 0) {
        const int4* dst4 = (const int4*)dst;
        const int4* src4 = (const int4*)src;
        int nq = E >> 2;
        int cq = (nq + B - 1) / B;
        int lo = b * cq, hi = min(nq, lo + cq);
        for (int i = lo + t; i < hi; i += KT) {
            int4 dv = dst4[i];
            int4 sv = src4[i];
            int p0 = atomicAdd(&cur[dv.x >> BSH], 1);
            pairs[p0] = ((unsigned)(dv.x & (BSZ - 1)) << 20) | (unsigned)sv.x;
            int p1 = atomicAdd(&cur[dv.y >> BSH], 1);
            pairs[p1] = ((unsigned)(dv.y & (BSZ - 1)) << 20) | (unsigned)sv.y;
            int p2 = atomicAdd(&cur[dv.z >> BSH], 1);
            pairs[p2] = ((unsigned)(dv.z & (BSZ - 1)) << 20) | (unsigned)sv.z;
            int p3 = atomicAdd(&cur[dv.w >> BSH], 1);
            pairs[p3] = ((unsigned)(dv.w & (BSZ - 1)) << 20) | (unsigned)sv.w;
        }
    } else {
        int ce = (E + B - 1) / B;
        int lo = b * ce, hi = min(E, lo + ce);
        for (int i = lo + t; i < hi; i += KT) {
            int d = dst[i];
            int p = atomicAdd(&cur[d >> BSH], 1);
            pairs[p] = ((unsigned)(d & (BSZ - 1)) << 20) | (unsigned)src[i];
        }
    }
}

// ---- K4: per-bucket node-sort (LDS-staged) -> csr + rowstart + dinv(zd.z); z = x@W12 ----
__global__ __launch_bounds__(KT) void k_csr_z(
        const unsigned* __restrict__ pairs, const int* __restrict__ dsum,
        const float* __restrict__ x, const float* __restrict__ W12,
        int* __restrict__ csr, int* __restrict__ rowstart,
        float4* __restrict__ zd, int N, int E, int NB) {
    __shared__ unsigned stage[STAGE_CAP];
    __shared__ int bst[512];
    __shared__ int h[BSZ];
    __shared__ int wtot[8];
    int t = threadIdx.x, b = blockIdx.x, B = gridDim.x;
    int lane = t & 63, w = t >> 6;

    int bsti = block_scan_dsum(dsum, NB, wtot);
    bst[t] = bsti;
    __syncthreads();

    for (int bb = b; bb < NB; bb += B) {
        int bs = bst[bb];
        int be = (bb + 1 < NB) ? bst[bb + 1] : E;
        int ne = be - bs;
        if (t < BSZ) h[t] = 0;
        __syncthreads();
        bool fits = (ne <= STAGE_CAP);
        if (fits) {
            for (int i = t; i < ne; i += KT) {
                unsigned p = pairs[bs + i];
                stage[i] = p;
                atomicAdd(&h[p >> 20], 1);
            }
        } else {
            for (int i = t; i < ne; i += KT) atomicAdd(&h[pairs[bs + i] >> 20], 1);
        }
        __syncthreads();
        int v = 0, inc = 0;
        if (t < BSZ) {
            v = h[t];
            inc = v;
#pragma unroll
            for (int o = 1; o < 64; o <<= 1) {
                int n = __shfl_up(inc, o);
                if (lane >= o) inc += n;
            }
            if (lane == 63) wtot[w] = inc;   // waves 0,1 only
        }
        __syncthreads();
        if (t < BSZ) {
            int excl = ((w == 1) ? wtot[0] : 0) + inc - v;
            int node = (bb << BSH) + t;
            if (node < N) {
                rowstart[node] = bs + excl;
                zd[node].z = rsqrtf((float)(v + 1));
            }
            h[t] = excl;                     // bucket-relative scatter cursor
        }
        __syncthreads();
        if (fits) {
            for (int i = t; i < ne; i += KT) {
                unsigned p = stage[i];
                int pos = bs + atomicAdd(&h[p >> 20], 1);
                csr[pos] = (int)(p & 0xFFFFFu);
            }
        } else {
            for (int i = t; i < ne; i += KT) {
                unsigned p = pairs[bs + i];
                int pos = bs + atomicAdd(&h[p >> 20], 1);
                csr[pos] = (int)(p & 0xFFFFFu);
            }
        }
        __syncthreads();
    }

    // ---- z = x @ W12, one wave per node row (writes zd.xy; .z disjoint) ----
    int nwaves = B * (KT >> 6);
    int wid = b * (KT >> 6) + w;
    float4 wv = *(const float4*)(W12 + lane * 4);
    for (int node = wid; node < N; node += nwaves) {
        float2 xv = *(const float2*)(x + (size_t)node * D + lane * 2);
        float p0 = fmaf(xv.x, wv.x, xv.y * wv.z);
        float p1 = fmaf(xv.x, wv.y, xv.y * wv.w);
#pragma unroll
        for (int o = 32; o > 0; o >>= 1) {
            p0 += __shfl_xor(p0, o);
            p1 += __shfl_xor(p1, o);
        }
        if (lane == 0) {
            float2 r; r.x = p0; r.y = p1;
            *(float2*)&zd[node] = r;
        }
    }
}

// ---- K5: gather A (16 lanes/node, register acc) -> aw = (w*a1x, w*a1y, srow, w) ----
__global__ void k_gatherA(const int* __restrict__ csr, const int* __restrict__ rowstart,
                          const float4* __restrict__ zd, float4* __restrict__ aw, int N) {
    int g = blockIdx.x * blockDim.x + threadIdx.x;
    int node = g >> 4, lane = threadIdx.x & 15;
    if (node >= N) return;
    int rs = rowstart[node], re = rowstart[node + 1];
    float acc0 = 0.f, acc1 = 0.f, sw = 0.f;
    for (int j = rs + lane; j < re; j += 16) {
        int s = csr[j];
        float4 zv = zd[s];                     // (z0, z1, dinv, -)
        acc0 = fmaf(zv.z, zv.x, acc0);
        acc1 = fmaf(zv.z, zv.y, acc1);
        sw  += zv.z;
    }
#pragma unroll
    for (int o = 8; o > 0; o >>= 1) {
        acc0 += __shfl_xor(acc0, o);
        acc1 += __shfl_xor(acc1, o);
        sw   += __shfl_xor(sw, o);
    }
    if (lane == 0) {
        float4 zv = zd[node];
        float wd = zv.z;
        float a1x  = wd * (acc0 + wd * zv.x);
        float a1y  = wd * (acc1 + wd * zv.y);
        float srow = wd * (sw + wd);
        aw[node] = make_float4(wd * a1x, wd * a1y, srow, wd);
    }
}

// ---- K6: gather B (16 lanes/node) + rank-1 bias + gumbel softmax epilogue ----
__global__ void k_gatherB(const int* __restrict__ csr, const int* __restrict__ rowstart,
                          const float4* __restrict__ aw, const float* __restrict__ cvec,
                          const float* __restrict__ b2, const float2* __restrict__ noise,
                          float2* __restrict__ out, int N) {
    int g = blockIdx.x * blockDim.x + threadIdx.x;
    int node = g >> 4, lane = threadIdx.x & 15;
    if (node >= N) return;
    int rs = rowstart[node], re = rowstart[node + 1];
    float acc0 = 0.f, acc1 = 0.f;
    for (int j = rs + lane; j < re; j += 16) {
        int s = csr[j];
        float4 av = aw[s];                     // (w*a1x, w*a1y, srow, w)
        acc0 += av.x;
        acc1 += av.y;
    }
#pragma unroll
    for (int o = 8; o > 0; o >>= 1) {
        acc0 += __shfl_xor(acc0, o);
        acc1 += __shfl_xor(acc1, o);
    }
    if (lane == 0) {
        float4 av = aw[node];
        float wd = av.w;
        float l0 = wd * (acc0 + av.x) + av.z * cvec[0] + b2[0];
        float l1 = wd * (acc1 + av.y) + av.z * cvec[1] + b2[1];
        const float EPS = 1e-9f;
        float2 nv = noise[node];
        float g0 = -logf(-logf(nv.x + EPS) + EPS);
        float g1 = -logf(-logf(nv.y + EPS) + EPS);
        float u0 = (l0 + g0) * 2.0f;
        float u1 = (l1 + g1) * 2.0f;
        float m = fmaxf(u0, u1);
        float e0 = __expf(u0 - m), e1 = __expf(u1 - m);
        float inv = 1.0f / (e0 + e1);
        float2 r; r.x = e0 * inv; r.y = e1 * inv;
        out[node] = r;
    }
}

extern "C" void kernel_launch(void* const* d_in, const int* in_sizes, int n_in,
                              void* d_out, int out_size, void* d_ws, size_t ws_size,
                              hipStream_t stream) {
    const float* x     = (const float*)d_in[0];
    const int*   ei    = (const int*)d_in[1];
    const float* W1    = (const float*)d_in[2];
    const float* b1    = (const float*)d_in[3];
    const float* W2    = (const float*)d_in[4];
    const float* b2    = (const float*)d_in[5];
    const float* noise = (const float*)d_in[6];
    float* out = (float*)d_out;

    const int N = in_sizes[0] / D;
    const int E = in_sizes[1] / 2;
    const int* src = ei;
    const int* dst = ei + E;
    const int NB = (N + BSZ - 1) >> BSH;       // buckets of 128 nodes (<=512)

    // ---- workspace carve (16B-aligned chunks first) ----
    char* p = (char*)d_ws;
    float4*   zd       = (float4*)p;   p += (size_t)N * 16;
    float4*   aw       = (float4*)p;   p += (size_t)N * 16;
    unsigned* pairs    = (unsigned*)p; p += (size_t)E * 4;
    int*      csr      = (int*)p;      p += (size_t)E * 4;
    int*      rowstart = (int*)p;      p += (size_t)(N + 4) * 4;
    int*      hist_t   = (int*)p;      p += (size_t)512 * GB1 * 4;   // 1 MB
    int*      dsum     = (int*)p;      p += 512 * 4;
    float*    W12      = (float*)p;    p += 256 * 4;
    float*    cvec     = (float*)p;    p += 16;

    int g16 = (N * 16 + 255) / 256;            // 16 lanes/node, 256-thr blocks

    k_hist<<<GB1, KT, 0, stream>>>(dst, hist_t, W1, b1, W2, W12, cvec, E, NB);
    k_scan_digit<<<NB, KT, 0, stream>>>(hist_t, dsum, rowstart, N, E);
    k_scatter_pairs<<<GB1, KT, 0, stream>>>(src, dst, hist_t, dsum, pairs, E, NB);
    k_csr_z<<<1024, KT, 0, stream>>>(pairs, dsum, x, W12, csr, rowstart, zd, N, E, NB);
    k_gatherA<<<g16, 256, 0, stream>>>(csr, rowstart, zd, aw, N);
    k_gatherB<<<g16, 256, 0, stream>>>(csr, rowstart, aw, cvec, b2, (const float2*)noise,
                                       (float2*)out, N);
}